// Round 1
// baseline (175.616 us; speedup 1.0000x reference)
//
#include <hip/hip_runtime.h>
#include <math.h>

#define BB 32
#define NN 1024
#define DD 512
#define SS 4
#define RR 64
#define OUTC 256          // SS*RR
#define NT (BB*NN)        // 32768 tokens

typedef float4 f4;

// ---------------- Gram: G[s] = S_s S_s^T (64x64), d-sliced with atomics ----
__global__ __launch_bounds__(256) void gram_kernel(const float* __restrict__ sub,
                                                   float* __restrict__ G) {
  __shared__ float A[RR][65];
  int s = blockIdx.x, dc = blockIdx.y;
  int t = threadIdx.x;
  for (int i = t; i < RR*64; i += 256) {
    int row = i >> 6, col = i & 63;
    A[row][col] = sub[(size_t)(s*RR + row)*DD + dc*64 + col];
  }
  __syncthreads();
  int r4 = t >> 4, c4 = t & 15;
  float acc[4][4] = {};
  for (int d = 0; d < 64; ++d) {
    float a[4], b[4];
#pragma unroll
    for (int i = 0; i < 4; ++i) a[i] = A[r4*4+i][d];
#pragma unroll
    for (int j = 0; j < 4; ++j) b[j] = A[c4*4+j][d];
#pragma unroll
    for (int i = 0; i < 4; ++i)
#pragma unroll
      for (int j = 0; j < 4; ++j) acc[i][j] += a[i]*b[j];
  }
#pragma unroll
  for (int i = 0; i < 4; ++i)
#pragma unroll
    for (int j = 0; j < 4; ++j)
      atomicAdd(&G[(size_t)(s*RR + r4*4+i)*RR + c4*4+j], acc[i][j]);
}

// ---------------- Main GEMM: y[tok][out] = sum_d x[tok][d]*sub[out][d] -----
// Also produces inv_norm per token as staging by-product.
__global__ __launch_bounds__(256) void gemm_kernel(const float* __restrict__ x,
                                                   const float* __restrict__ sub,
                                                   float* __restrict__ y,
                                                   float* __restrict__ invn) {
  __shared__ float A[32][68];    // k-major token tile (pad 68 keeps f4 align)
  __shared__ float Bs[32][260];  // k-major output tile
  __shared__ float ssq[64][9];
  int t = threadIdx.x;
  int m0 = blockIdx.x * 64;
  int tm = t >> 5, tn = t & 31;
  int arow0 = t >> 3, ac4 = t & 7;
  float acc[8][8] = {};
  float ps0 = 0.f, ps1 = 0.f;
  for (int kc = 0; kc < DD; kc += 32) {
    __syncthreads();
    // stage A: 64 tokens x 32 d
    {
      f4 v = *(const f4*)&x[(size_t)(m0 + arow0)*DD + kc + ac4*4];
      A[ac4*4+0][arow0] = v.x; A[ac4*4+1][arow0] = v.y;
      A[ac4*4+2][arow0] = v.z; A[ac4*4+3][arow0] = v.w;
      ps0 += v.x*v.x + v.y*v.y + v.z*v.z + v.w*v.w;
      f4 u = *(const f4*)&x[(size_t)(m0 + arow0 + 32)*DD + kc + ac4*4];
      A[ac4*4+0][arow0+32] = u.x; A[ac4*4+1][arow0+32] = u.y;
      A[ac4*4+2][arow0+32] = u.z; A[ac4*4+3][arow0+32] = u.w;
      ps1 += u.x*u.x + u.y*u.y + u.z*u.z + u.w*u.w;
    }
    // stage B: 256 outputs x 32 d
#pragma unroll
    for (int r = 0; r < 8; ++r) {
      int q = t + 256*r;
      int row = q >> 3, c4 = q & 7;
      f4 v = *(const f4*)&sub[(size_t)row*DD + kc + c4*4];
      Bs[c4*4+0][row] = v.x; Bs[c4*4+1][row] = v.y;
      Bs[c4*4+2][row] = v.z; Bs[c4*4+3][row] = v.w;
    }
    __syncthreads();
#pragma unroll
    for (int k = 0; k < 32; ++k) {
      float a[8], b[8];
      *(f4*)&a[0] = *(const f4*)&A[k][tm*8];
      *(f4*)&a[4] = *(const f4*)&A[k][tm*8+4];
      *(f4*)&b[0] = *(const f4*)&Bs[k][tn*8];
      *(f4*)&b[4] = *(const f4*)&Bs[k][tn*8+4];
#pragma unroll
      for (int i = 0; i < 8; ++i)
#pragma unroll
        for (int j = 0; j < 8; ++j)
          acc[i][j] += a[i]*b[j];
    }
  }
#pragma unroll
  for (int i = 0; i < 8; ++i) {
    f4 v0 = {acc[i][0], acc[i][1], acc[i][2], acc[i][3]};
    f4 v1 = {acc[i][4], acc[i][5], acc[i][6], acc[i][7]};
    size_t base = (size_t)(m0 + tm*8 + i)*OUTC + tn*8;
    *(f4*)&y[base]   = v0;
    *(f4*)&y[base+4] = v1;
  }
  ssq[arow0][ac4]    = ps0;
  ssq[arow0+32][ac4] = ps1;
  __syncthreads();
  if (t < 64) {
    float ss = 0.f;
#pragma unroll
    for (int j = 0; j < 8; ++j) ss += ssq[t][j];
    invn[m0 + t] = 1.f / fmaxf(sqrtf(ss), 1e-12f);
  }
}

// ---------------- projection (y^T G y per s) + sparsemax + argmax ----------
__global__ __launch_bounds__(256) void proj_kernel(const float* __restrict__ y,
                                                   const float* __restrict__ G,
                                                   const float* __restrict__ invn,
                                                   float inv_denom,
                                                   float* __restrict__ prob,
                                                   int* __restrict__ amax) {
  __shared__ float yl[64][257];   // odd pad: conflict-light scalar reads
  __shared__ float qp[SS][8][64];
  __shared__ float pr[64][5];
  int t = threadIdx.x;
  int m0 = blockIdx.x * 64;
  for (int i = t; i < 64*64; i += 256) {
    int tok = i >> 6, c4 = i & 63;
    f4 v = *(const f4*)&y[(size_t)(m0+tok)*OUTC + c4*4];
    yl[tok][c4*4+0] = v.x; yl[tok][c4*4+1] = v.y;
    yl[tok][c4*4+2] = v.z; yl[tok][c4*4+3] = v.w;
  }
  __syncthreads();
  int s = t >> 6, u = t & 63, tokG = u >> 3, kG = u & 7;
  const float* Gp = G + (size_t)s*RR*RR;
  float z[8][8] = {};
  for (int kp = 0; kp < RR; ++kp) {
    float a[8], b[8];
    *(f4*)&a[0] = *(const f4*)&Gp[kp*RR + kG*8];
    *(f4*)&a[4] = *(const f4*)&Gp[kp*RR + kG*8 + 4];
#pragma unroll
    for (int i = 0; i < 8; ++i) b[i] = yl[tokG*8+i][s*RR + kp];
#pragma unroll
    for (int i = 0; i < 8; ++i)
#pragma unroll
      for (int j = 0; j < 8; ++j)
        z[i][j] += b[i]*a[j];
  }
#pragma unroll
  for (int i = 0; i < 8; ++i) {
    float q = 0.f;
#pragma unroll
    for (int j = 0; j < 8; ++j)
      q += z[i][j] * yl[tokG*8+i][s*RR + kG*8 + j];
    qp[s][kG][tokG*8+i] = q;
  }
  __syncthreads();
  {
    int tok = t & 63, s2 = t >> 6;
    float q = 0.f;
#pragma unroll
    for (int g = 0; g < 8; ++g) q += qp[s2][g][tok];
    pr[tok][s2] = sqrtf(fmaxf(q, 0.f)) * invn[m0+tok] * inv_denom;
  }
  __syncthreads();
  if (t < 64) {
    float p0 = pr[t][0], p1 = pr[t][1], p2 = pr[t][2], p3 = pr[t][3];
    float a0=p0, a1=p1, a2=p2, a3=p3, hi, lo;
    hi = fmaxf(a0,a1); lo = fminf(a0,a1); a0=hi; a1=lo;
    hi = fmaxf(a2,a3); lo = fminf(a2,a3); a2=hi; a3=lo;
    hi = fmaxf(a0,a2); lo = fminf(a0,a2); a0=hi; a2=lo;
    hi = fmaxf(a1,a3); lo = fminf(a1,a3); a1=hi; a3=lo;
    hi = fmaxf(a1,a2); lo = fminf(a1,a2); a1=hi; a2=lo;
    float c2 = a0+a1, c3 = c2+a2, c4s = c3+a3;
    int ksup = 1 + (2.f*a1 > c2-1.f) + (3.f*a2 > c3-1.f) + (4.f*a3 > c4s-1.f);
    float csel = (ksup==1) ? a0 : (ksup==2) ? c2 : (ksup==3) ? c3 : c4s;
    float tau = (csel - 1.f) / (float)ksup;
    float q0 = fmaxf(p0-tau, 0.f), q1 = fmaxf(p1-tau, 0.f);
    float q2 = fmaxf(p2-tau, 0.f), q3 = fmaxf(p3-tau, 0.f);
    int arg = 0; float best = q0;
    if (q1 > best) { best = q1; arg = 1; }
    if (q2 > best) { best = q2; arg = 2; }
    if (q3 > best) { best = q3; arg = 3; }
    f4 o = {q0,q1,q2,q3};
    *(f4*)&prob[(size_t)(m0+t)*4] = o;
    amax[m0+t] = arg;
  }
}

// ---------------- majority vote over valid tokens + combined weights -------
__global__ __launch_bounds__(256) void vote_kernel(const int* __restrict__ amax,
                                                   const float* __restrict__ prob,
                                                   const float* __restrict__ invn,
                                                   const int* __restrict__ mask,
                                                   float* __restrict__ wgt) {
  __shared__ int cnt[4];
  __shared__ int vsh;
  int b = blockIdx.x, t = threadIdx.x;
  if (t < 4) cnt[t] = 0;
  __syncthreads();
  int m = mask[b];
  int c0=0,c1=0,c2=0,c3=0;
  for (int n = t; n < NN; n += 256) {
    if (n < m) {
      int a = amax[b*NN + n];
      c0 += (a==0); c1 += (a==1); c2 += (a==2); c3 += (a==3);
    }
  }
  atomicAdd(&cnt[0], c0); atomicAdd(&cnt[1], c1);
  atomicAdd(&cnt[2], c2); atomicAdd(&cnt[3], c3);
  __syncthreads();
  if (t == 0) {
    int arg = 0, best = cnt[0];
    if (cnt[1] > best) { best = cnt[1]; arg = 1; }
    if (cnt[2] > best) { best = cnt[2]; arg = 2; }
    if (cnt[3] > best) { best = cnt[3]; arg = 3; }
    vsh = arg;
  }
  __syncthreads();
  int v = vsh;
  for (int n = t; n < NN; n += 256)
    wgt[b*NN + n] = prob[(size_t)(b*NN + n)*4 + v] * invn[b*NN + n];
}

// ---------------- feature = sum_n x*inv_norm*w (two-stage, deterministic) --
__global__ __launch_bounds__(256) void feat_partial_kernel(const float* __restrict__ x,
                                                           const float* __restrict__ wgt,
                                                           float* __restrict__ partial) {
  int b = blockIdx.x, nc = blockIdx.y, t = threadIdx.x;
  int nl = t >> 7, sl = t & 127;
  f4 acc = {0.f,0.f,0.f,0.f};
  for (int n = nc*64 + nl; n < nc*64 + 64; n += 2) {
    float w = wgt[b*NN + n];
    f4 v = *(const f4*)&x[((size_t)b*NN + n)*DD + sl*4];
    acc.x += v.x*w; acc.y += v.y*w; acc.z += v.z*w; acc.w += v.w*w;
  }
  *(f4*)&partial[(((size_t)b*16 + nc)*2 + nl)*DD + sl*4] = acc;
}

__global__ __launch_bounds__(256) void feat_reduce_kernel(const float* __restrict__ partial,
                                                          float* __restrict__ out) {
  int i = blockIdx.x*256 + threadIdx.x;
  int b = i >> 9, d = i & 511;
  float f = 0.f;
#pragma unroll
  for (int c = 0; c < 32; ++c)
    f += partial[((size_t)b*32 + c)*DD + d];
  out[i] = f;
}

extern "C" void kernel_launch(void* const* d_in, const int* in_sizes, int n_in,
                              void* d_out, int out_size, void* d_ws, size_t ws_size,
                              hipStream_t stream) {
  const float* x    = (const float*)d_in[0];
  const int*   mask = (const int*)d_in[1];
  const float* sub  = (const float*)d_in[2];
  float* out = (float*)d_out;

  float* ws   = (float*)d_ws;
  float* y    = ws;                        // 32768*256 f32 = 32 MB
  float* G    = y + (size_t)NT*OUTC;       // 4*64*64
  float* invn = G + SS*RR*RR;              // 32768
  float* prob = invn + NT;                 // 32768*4
  int*   amax = (int*)(prob + (size_t)NT*4); // 32768 ints
  float* wgt  = (float*)(amax + NT);       // 32768
  float* partial = wgt + NT;               // 32*32*512 = 524288

  // SCALE = 1.718*exp(-count/30000) - 0.718, count = B = 32
  double scale = 1.718 * exp(-((double)BB) / 30000.0) - 0.718;
  float inv_denom = (float)(1.0 / ((double)DD * scale));

  hipMemsetAsync(G, 0, SS*RR*RR*sizeof(float), stream);
  gram_kernel<<<dim3(SS, 8), 256, 0, stream>>>(sub, G);
  gemm_kernel<<<NT/64, 256, 0, stream>>>(x, sub, y, invn);
  proj_kernel<<<NT/64, 256, 0, stream>>>(y, G, invn, inv_denom, prob, amax);
  vote_kernel<<<BB, 256, 0, stream>>>(amax, prob, invn, mask, wgt);
  feat_partial_kernel<<<dim3(BB, 16), 256, 0, stream>>>(x, wgt, partial);
  feat_reduce_kernel<<<BB*DD/256, 256, 0, stream>>>(partial, out);
}

// Round 2
// 98.490 us; speedup vs baseline: 1.7831x; 1.7831x over previous
//
#include <hip/hip_runtime.h>
#include <math.h>

#define BB 32
#define NN 1024
#define DD 512
#define SS 4
#define RR 64
#define OUTC 256          // SS*RR
#define NT (BB*NN)        // 32768 tokens

typedef float4 f4;        // HIP float4 for the simple kernels
typedef float f32x4 __attribute__((ext_vector_type(4)));
typedef __bf16 bf16x8 __attribute__((ext_vector_type(8)));
typedef unsigned short u16x8 __attribute__((ext_vector_type(8)));
typedef const __attribute__((address_space(1))) void GVoid;
typedef __attribute__((address_space(3))) void LVoid;

union BF8 { u16x8 u; bf16x8 b; };

__device__ __forceinline__ unsigned short f2bf(float f) {
  unsigned int u = __float_as_uint(f);
  return (unsigned short)((u + 0x7fffu + ((u >> 16) & 1u)) >> 16);
}
__device__ __forceinline__ float bf2f(unsigned short h) {
  return __uint_as_float(((unsigned int)h) << 16);
}

// ---------------- Gram: G[s] = S_s S_s^T (64x64), d-sliced with atomics ----
__global__ __launch_bounds__(256) void gram_kernel(const float* __restrict__ sub,
                                                   float* __restrict__ G) {
  __shared__ float A[RR][65];
  int s = blockIdx.x, dc = blockIdx.y;
  int t = threadIdx.x;
  for (int i = t; i < RR*64; i += 256) {
    int row = i >> 6, col = i & 63;
    A[row][col] = sub[(size_t)(s*RR + row)*DD + dc*64 + col];
  }
  __syncthreads();
  int r4 = t >> 4, c4 = t & 15;
  float acc[4][4] = {};
  for (int d = 0; d < 64; ++d) {
    float a[4], b[4];
#pragma unroll
    for (int i = 0; i < 4; ++i) a[i] = A[r4*4+i][d];
#pragma unroll
    for (int j = 0; j < 4; ++j) b[j] = A[c4*4+j][d];
#pragma unroll
    for (int i = 0; i < 4; ++i)
#pragma unroll
      for (int j = 0; j < 4; ++j) acc[i][j] += a[i]*b[j];
  }
#pragma unroll
  for (int i = 0; i < 4; ++i)
#pragma unroll
    for (int j = 0; j < 4; ++j)
      atomicAdd(&G[(size_t)(s*RR + r4*4+i)*RR + c4*4+j], acc[i][j]);
}

// ---------------- convert sub and G to bf16 hi/lo --------------------------
__global__ __launch_bounds__(256) void cvt_kernel(const float* __restrict__ sub,
                                                  const float* __restrict__ G,
                                                  unsigned short* __restrict__ subhi,
                                                  unsigned short* __restrict__ sublo,
                                                  unsigned short* __restrict__ Ghi,
                                                  unsigned short* __restrict__ Glo) {
  int i = blockIdx.x*256 + threadIdx.x;
  if (i < OUTC*DD) {
    float f = sub[i];
    unsigned short h = f2bf(f);
    subhi[i] = h;
    sublo[i] = f2bf(f - bf2f(h));
  }
  int j = i - OUTC*DD;
  if (j >= 0 && j < SS*RR*RR) {
    float f = G[j];
    unsigned short h = f2bf(f);
    Ghi[j] = h;
    Glo[j] = f2bf(f - bf2f(h));
  }
}

// ---------------- fused: y = x*sub^T (MFMA hi/lo), q = y^T G y, sparsemax --
// Block: 256 thr = 4 waves, wave w owns subspace s=w. M-tile = 64 tokens.
__global__ __launch_bounds__(256, 2) void fused_kernel(const float* __restrict__ x,
    const unsigned short* __restrict__ subhi, const unsigned short* __restrict__ sublo,
    const unsigned short* __restrict__ Ghi, const unsigned short* __restrict__ Glo,
    float inv_denom,
    float* __restrict__ prob, int* __restrict__ amax, float* __restrict__ invn) {
  __shared__ float ldsA[2][2048];      // 2 x 8KB: 64 tokens x 32 k f32, XOR-swizzled
  __shared__ float ylds[4][32*68];     // per-wave y half-tile, padded stride 68
  __shared__ float ssqlds[256];
  __shared__ float prqlds[256];        // prq[tok][s]

  int t = threadIdx.x;
  int lane = t & 63;
  int w = t >> 6;                      // wave id == subspace s
  int l15 = lane & 15;
  int l4  = (lane >> 4) & 3;
  int m0 = blockIdx.x * 64;

  f32x4 acc[4][4] = {};                // y C-frags: [mf][nf]
  float ssq = 0.f;

  // --- stage one 64x32 f32 chunk into LDS (linear dest, swizzled source) ---
  auto stage = [&](int bufsel, int kc) {
#pragma unroll
    for (int q = 0; q < 2; ++q) {
      int g = t + q*256;               // granule 0..511 (16B units)
      int row = g >> 3, gp = g & 7;
      int gl = gp ^ (row & 7);         // swizzle involution
      const float* src = &x[(size_t)(m0+row)*DD + kc*32 + gl*4];
      __builtin_amdgcn_global_load_lds((GVoid*)src,
          (LVoid*)((char*)&ldsA[bufsel][0] + (size_t)g*16), 16, 0, 0);
    }
  };
  // --- load B-fragments (sub rows, bf16 hi/lo, contiguous 16B) -------------
  auto loadB = [&](BF8 (&bh)[4], BF8 (&bl)[4], int kc) {
#pragma unroll
    for (int nf = 0; nf < 4; ++nf) {
      size_t off = (size_t)(w*64 + nf*16 + l15)*DD + kc*32 + l4*8;
      bh[nf].u = *(const u16x8*)&subhi[off];
      bl[nf].u = *(const u16x8*)&sublo[off];
    }
  };
  // --- one k-step: ssq + A-frags + 48 MFMAs --------------------------------
  auto kstep = [&](int bufsel, BF8 (&bh)[4], BF8 (&bl)[4]) {
    { // ssq partial: row t&63, k-slot t>>6 (8 f32)
      int row = t & 63, glp = (t >> 6)*2;
      int gp0 = glp ^ (row & 7), gp1 = (glp+1) ^ (row & 7);
      f32x4 v0 = *(f32x4*)&ldsA[bufsel][(row*8+gp0)*4];
      f32x4 v1 = *(f32x4*)&ldsA[bufsel][(row*8+gp1)*4];
      ssq += v0[0]*v0[0]+v0[1]*v0[1]+v0[2]*v0[2]+v0[3]*v0[3]
           + v1[0]*v1[0]+v1[1]*v1[1]+v1[2]*v1[2]+v1[3]*v1[3];
    }
    BF8 ah[4], al[4];
#pragma unroll
    for (int mf = 0; mf < 4; ++mf) {
      int row = mf*16 + l15;
      int gl0 = l4*2;
      int gp0 = gl0 ^ (row & 7), gp1 = (gl0+1) ^ (row & 7);
      f32x4 v0 = *(f32x4*)&ldsA[bufsel][(row*8+gp0)*4];
      f32x4 v1 = *(f32x4*)&ldsA[bufsel][(row*8+gp1)*4];
      float f[8] = {v0[0],v0[1],v0[2],v0[3],v1[0],v1[1],v1[2],v1[3]};
#pragma unroll
      for (int e = 0; e < 8; ++e) {
        unsigned short h = f2bf(f[e]);
        ah[mf].u[e] = h;
        al[mf].u[e] = f2bf(f[e] - bf2f(h));
      }
    }
#pragma unroll
    for (int nf = 0; nf < 4; ++nf)
#pragma unroll
      for (int mf = 0; mf < 4; ++mf) {
        acc[mf][nf] = __builtin_amdgcn_mfma_f32_16x16x32_bf16(ah[mf].b, bh[nf].b, acc[mf][nf], 0,0,0);
        acc[mf][nf] = __builtin_amdgcn_mfma_f32_16x16x32_bf16(ah[mf].b, bl[nf].b, acc[mf][nf], 0,0,0);
        acc[mf][nf] = __builtin_amdgcn_mfma_f32_16x16x32_bf16(al[mf].b, bh[nf].b, acc[mf][nf], 0,0,0);
      }
  };

  BF8 bhA[4], blA[4], bhB[4], blB[4];
  stage(0, 0);
  loadB(bhA, blA, 0);
  for (int kc = 0; kc < 16; kc += 2) {
    __syncthreads();                       // buf0(kc) staged & readable
    stage(1, kc+1); loadB(bhB, blB, kc+1); // prefetch next
    kstep(0, bhA, blA);
    __syncthreads();                       // buf1(kc+1) staged & readable
    if (kc < 14) { stage(0, kc+2); loadB(bhA, blA, kc+2); }
    kstep(1, bhB, blB);
  }

  // --- q = y^T G y via z = y*G (MFMA, G bf16 hi/lo, symmetric) -------------
  BF8 gh[2][4], gl2[2][4];
#pragma unroll
  for (int kf = 0; kf < 2; ++kf)
#pragma unroll
    for (int nf = 0; nf < 4; ++nf) {
      size_t off = (size_t)(w*64 + nf*16 + l15)*64 + kf*32 + l4*8;
      gh[kf][nf].u  = *(const u16x8*)&Ghi[off];
      gl2[kf][nf].u = *(const u16x8*)&Glo[off];
    }
  float* yw = &ylds[w][0];
#pragma unroll
  for (int h = 0; h < 2; ++h) {
    // write y half-tile (32 tokens) to private LDS
#pragma unroll
    for (int mf2 = 0; mf2 < 2; ++mf2)
#pragma unroll
      for (int nf = 0; nf < 4; ++nf)
#pragma unroll
        for (int r = 0; r < 4; ++r)
          yw[(mf2*16 + l4*4 + r)*68 + nf*16 + l15] = acc[2*h+mf2][nf][r];
    // read back as A-frags, split hi/lo
    BF8 yh[2][2], yl[2][2];
#pragma unroll
    for (int mf2 = 0; mf2 < 2; ++mf2)
#pragma unroll
      for (int kf = 0; kf < 2; ++kf) {
        int base = (mf2*16 + l15)*68 + kf*32 + l4*8;
        f32x4 v0 = *(f32x4*)&yw[base];
        f32x4 v1 = *(f32x4*)&yw[base+4];
        float f[8] = {v0[0],v0[1],v0[2],v0[3],v1[0],v1[1],v1[2],v1[3]};
#pragma unroll
        for (int e = 0; e < 8; ++e) {
          unsigned short hh = f2bf(f[e]);
          yh[mf2][kf].u[e] = hh;
          yl[mf2][kf].u[e] = f2bf(f[e] - bf2f(hh));
        }
      }
    f32x4 z[2][4] = {};
#pragma unroll
    for (int mf2 = 0; mf2 < 2; ++mf2)
#pragma unroll
      for (int nf = 0; nf < 4; ++nf)
#pragma unroll
        for (int kf = 0; kf < 2; ++kf) {
          z[mf2][nf] = __builtin_amdgcn_mfma_f32_16x16x32_bf16(yh[mf2][kf].b, gh[kf][nf].b,  z[mf2][nf], 0,0,0);
          z[mf2][nf] = __builtin_amdgcn_mfma_f32_16x16x32_bf16(yh[mf2][kf].b, gl2[kf][nf].b, z[mf2][nf], 0,0,0);
          z[mf2][nf] = __builtin_amdgcn_mfma_f32_16x16x32_bf16(yl[mf2][kf].b, gh[kf][nf].b,  z[mf2][nf], 0,0,0);
        }
    // q[tok] = sum_j z[tok][j]*y[tok][j]; reduce over the 16 col-lanes
#pragma unroll
    for (int mf2 = 0; mf2 < 2; ++mf2)
#pragma unroll
      for (int r = 0; r < 4; ++r) {
        float qp = 0.f;
#pragma unroll
        for (int nf = 0; nf < 4; ++nf)
          qp += z[mf2][nf][r] * acc[2*h+mf2][nf][r];
        qp += __shfl_xor(qp, 1);
        qp += __shfl_xor(qp, 2);
        qp += __shfl_xor(qp, 4);
        qp += __shfl_xor(qp, 8);
        if (l15 == 0) {
          int tok = (2*h+mf2)*16 + l4*4 + r;
          prqlds[tok*4 + w] = qp;
        }
      }
  }
  ssqlds[(t & 63)*4 + (t >> 6)] = ssq;
  __syncthreads();

  // --- sparsemax over S=4 + argmax + invn ----------------------------------
  if (t < 64) {
    float ss = ssqlds[t*4] + ssqlds[t*4+1] + ssqlds[t*4+2] + ssqlds[t*4+3];
    float inv = 1.f / fmaxf(sqrtf(ss), 1e-12f);
    float p0 = sqrtf(fmaxf(prqlds[t*4+0], 0.f)) * inv * inv_denom;
    float p1 = sqrtf(fmaxf(prqlds[t*4+1], 0.f)) * inv * inv_denom;
    float p2 = sqrtf(fmaxf(prqlds[t*4+2], 0.f)) * inv * inv_denom;
    float p3 = sqrtf(fmaxf(prqlds[t*4+3], 0.f)) * inv * inv_denom;
    float a0=p0, a1=p1, a2=p2, a3=p3, hi, lo;
    hi = fmaxf(a0,a1); lo = fminf(a0,a1); a0=hi; a1=lo;
    hi = fmaxf(a2,a3); lo = fminf(a2,a3); a2=hi; a3=lo;
    hi = fmaxf(a0,a2); lo = fminf(a0,a2); a0=hi; a2=lo;
    hi = fmaxf(a1,a3); lo = fminf(a1,a3); a1=hi; a3=lo;
    hi = fmaxf(a1,a2); lo = fminf(a1,a2); a1=hi; a2=lo;
    float c2 = a0+a1, c3 = c2+a2, c4s = c3+a3;
    int ksup = 1 + (2.f*a1 > c2-1.f) + (3.f*a2 > c3-1.f) + (4.f*a3 > c4s-1.f);
    float csel = (ksup==1) ? a0 : (ksup==2) ? c2 : (ksup==3) ? c3 : c4s;
    float tau = (csel - 1.f) / (float)ksup;
    float q0 = fmaxf(p0-tau, 0.f), q1 = fmaxf(p1-tau, 0.f);
    float q2 = fmaxf(p2-tau, 0.f), q3 = fmaxf(p3-tau, 0.f);
    int arg = 0; float best = q0;
    if (q1 > best) { best = q1; arg = 1; }
    if (q2 > best) { best = q2; arg = 2; }
    if (q3 > best) { best = q3; arg = 3; }
    f4 o = {q0,q1,q2,q3};
    *(f4*)&prob[(size_t)(m0+t)*4] = o;
    amax[m0+t] = arg;
    invn[m0+t] = inv;
  }
}

// ---------------- majority vote over valid tokens + combined weights -------
__global__ __launch_bounds__(256) void vote_kernel(const int* __restrict__ amax,
                                                   const float* __restrict__ prob,
                                                   const float* __restrict__ invn,
                                                   const int* __restrict__ mask,
                                                   float* __restrict__ wgt) {
  __shared__ int cnt[4];
  __shared__ int vsh;
  int b = blockIdx.x, t = threadIdx.x;
  if (t < 4) cnt[t] = 0;
  __syncthreads();
  int m = mask[b];
  int c0=0,c1=0,c2=0,c3=0;
  for (int n = t; n < NN; n += 256) {
    if (n < m) {
      int a = amax[b*NN + n];
      c0 += (a==0); c1 += (a==1); c2 += (a==2); c3 += (a==3);
    }
  }
  atomicAdd(&cnt[0], c0); atomicAdd(&cnt[1], c1);
  atomicAdd(&cnt[2], c2); atomicAdd(&cnt[3], c3);
  __syncthreads();
  if (t == 0) {
    int arg = 0, best = cnt[0];
    if (cnt[1] > best) { best = cnt[1]; arg = 1; }
    if (cnt[2] > best) { best = cnt[2]; arg = 2; }
    if (cnt[3] > best) { best = cnt[3]; arg = 3; }
    vsh = arg;
  }
  __syncthreads();
  int v = vsh;
  for (int n = t; n < NN; n += 256)
    wgt[b*NN + n] = prob[(size_t)(b*NN + n)*4 + v] * invn[b*NN + n];
}

// ---------------- feature = sum_n x*inv_norm*w (two-stage, deterministic) --
__global__ __launch_bounds__(256) void feat_partial_kernel(const float* __restrict__ x,
                                                           const float* __restrict__ wgt,
                                                           float* __restrict__ partial) {
  int b = blockIdx.x, nc = blockIdx.y, t = threadIdx.x;
  int nl = t >> 7, sl = t & 127;
  f4 acc = {0.f,0.f,0.f,0.f};
  for (int n = nc*64 + nl; n < nc*64 + 64; n += 2) {
    float w = wgt[b*NN + n];
    f4 v = *(const f4*)&x[((size_t)b*NN + n)*DD + sl*4];
    acc.x += v.x*w; acc.y += v.y*w; acc.z += v.z*w; acc.w += v.w*w;
  }
  *(f4*)&partial[(((size_t)b*16 + nc)*2 + nl)*DD + sl*4] = acc;
}

__global__ __launch_bounds__(256) void feat_reduce_kernel(const float* __restrict__ partial,
                                                          float* __restrict__ out) {
  int i = blockIdx.x*256 + threadIdx.x;
  int b = i >> 9, d = i & 511;
  float f = 0.f;
#pragma unroll
  for (int c = 0; c < 32; ++c)
    f += partial[((size_t)b*32 + c)*DD + d];
  out[i] = f;
}

extern "C" void kernel_launch(void* const* d_in, const int* in_sizes, int n_in,
                              void* d_out, int out_size, void* d_ws, size_t ws_size,
                              hipStream_t stream) {
  const float* x    = (const float*)d_in[0];
  const int*   mask = (const int*)d_in[1];
  const float* sub  = (const float*)d_in[2];
  float* out = (float*)d_out;

  float* ws   = (float*)d_ws;
  float* G      = ws;                              // 16384 f32
  float* invn   = G + SS*RR*RR;                    // 32768
  float* prob   = invn + NT;                       // 131072
  int*   amax   = (int*)(prob + (size_t)NT*4);     // 32768
  float* wgt    = (float*)(amax + NT);             // 32768
  float* partial= wgt + NT;                        // 524288
  unsigned short* subhi = (unsigned short*)(partial + (size_t)BB*32*DD);
  unsigned short* sublo = subhi + OUTC*DD;
  unsigned short* Ghi   = sublo + OUTC*DD;
  unsigned short* Glo   = Ghi + SS*RR*RR;

  double scale = 1.718 * exp(-((double)BB) / 30000.0) - 0.718;
  float inv_denom = (float)(1.0 / ((double)DD * scale));

  hipMemsetAsync(G, 0, SS*RR*RR*sizeof(float), stream);
  gram_kernel<<<dim3(SS, 8), 256, 0, stream>>>(sub, G);
  cvt_kernel<<<(OUTC*DD + SS*RR*RR + 255)/256, 256, 0, stream>>>(sub, G, subhi, sublo, Ghi, Glo);
  fused_kernel<<<NT/64, 256, 0, stream>>>(x, subhi, sublo, Ghi, Glo, inv_denom, prob, amax, invn);
  vote_kernel<<<BB, 256, 0, stream>>>(amax, prob, invn, mask, wgt);
  feat_partial_kernel<<<dim3(BB, 16), 256, 0, stream>>>(x, wgt, partial);
  feat_reduce_kernel<<<BB*DD/256, 256, 0, stream>>>(partial, out);
}